// Round 8
// baseline (183.200 us; speedup 1.0000x reference)
//
#include <hip/hip_runtime.h>
#include <stdint.h>

// N=4096, D=1024 -> M = [Q|K] : 4096 x 2048, Mt = M^T (fp8 e4m3, K-permuted)
// loss = [ sum_{a,b} s_a s_b (M^T M)_ab^2 ] / (N*(N-1)), s_a=+1 (a<1024), -1 else
// R8: (1) fused prep (norm+transpose+fp8) with coalesced reads via LDS byte-tile
//     (old transpose had 4B/4KB-stride scalar reads = 16-32x amplification);
//     (2) gram tail fuses the square-reduce via per-tile atomic counters
//         (last kc-block sums 4 bf16 slabs in fp32, squares, atomicAdds);
//     (3) XCD-aware job swizzle for A-panel L2 locality. 2 kernels total.
#define N_ROWS 4096
#define DIMS   1024
#define BM 128
#define BK 128         // fp8 elements per LDS row = 128 bytes
#define TG 16
#define NTRI 136
#define KSPLIT 4
#define KCHUNK 1024    // 4096/KSPLIT (fp8 bytes)
#define NITER  (KCHUNK / BK)   // 8
#define NJOBS  (NTRI * KSPLIT) // 544 = 68 * 8

typedef __attribute__((ext_vector_type(2))) long longx2;
typedef __attribute__((ext_vector_type(4))) float f32x4;

__device__ __forceinline__ unsigned short f2bf(float f) {
  union { float f; unsigned int u; } c; c.f = f;
  unsigned int u = c.u;
  return (unsigned short)((u + 0x7fffu + ((u >> 16) & 1u)) >> 16);
}
__device__ __forceinline__ float bf2f(unsigned short v) {
  union { float f; unsigned int u; } c; c.u = ((unsigned int)v) << 16;
  return c.f;
}
// pack 4 floats -> 4 fp8 e4m3 bytes (hardware cvt, OCP on gfx950)
__device__ __forceinline__ unsigned int pk4_fp8(float a, float b, float c, float d) {
  int v = __builtin_amdgcn_cvt_pk_fp8_f32(a, b, 0, false);
  v = __builtin_amdgcn_cvt_pk_fp8_f32(c, d, v, true);
  return (unsigned int)v;
}
// async global->LDS, 16B/lane
__device__ __forceinline__ void async_cp16(const unsigned char* g, void* lds) {
  __builtin_amdgcn_global_load_lds(
      (const __attribute__((address_space(1))) void*)g,
      (__attribute__((address_space(3))) void*)lds, 16, 0, 0);
}

// ---------------------------------------------------------------------------
// K1: fused prep. Block = 16 rows of one source (grid 256 x {q,k}).
// Phase 1: row norms from coalesced float4 reads. Phase 2: re-read same rows
// (L2-hot), scale, fp8-pack, transpose via LDS byte tile (double-buffered),
// write Mt K-permuted. Also zeroes d_out and the per-tile counters.
// ---------------------------------------------------------------------------
__global__ __launch_bounds__(256) void prep_kernel(
    const float* __restrict__ fq, const float* __restrict__ fk,
    unsigned char* __restrict__ Mt, float* __restrict__ out,
    int* __restrict__ counters) {
  if (blockIdx.x == 0 && blockIdx.y == 0) {
    if (threadIdx.x == 0) out[0] = 0.0f;
    if (threadIdx.x < NTRI) counters[threadIdx.x] = 0;
  }
  const int i0 = blockIdx.x * 16;
  const float* src = blockIdx.y ? fk : fq;
  const int aBase = blockIdx.y ? DIMS : 0;

  __shared__ float invLds[16];
  __shared__ unsigned char tile8[2][64 * 20];  // [buf][a_local*20 + i], pitch 20

  const int w = threadIdx.x >> 6, lane = threadIdx.x & 63;
  // phase 1: each wave computes 4 row norms
  #pragma unroll
  for (int rr = 0; rr < 4; ++rr) {
    const int r = w * 4 + rr;
    const float4* s4 = (const float4*)(src + (size_t)(i0 + r) * DIMS);
    float ss = 0.0f;
    #pragma unroll
    for (int s = 0; s < 4; ++s) {
      float4 v = s4[lane + 64 * s];
      ss += v.x * v.x + v.y * v.y + v.z * v.z + v.w * v.w;
    }
    #pragma unroll
    for (int off = 32; off > 0; off >>= 1) ss += __shfl_xor(ss, off);
    if (lane == 0) invLds[r] = 1.0f / sqrtf(ss);  // eps cancel ~3e-9 rel
  }
  __syncthreads();

  // K-permutation constants: i = s1*64+s0*32+q*8+j -> pos = q*32+s1*16+s0*8+j
  const int iloc = i0 & 127;        // 16-aligned offset within 128-block
  const int blk = i0 >> 7;
  const int ti = threadIdx.x >> 4;          // load side: i 0..15
  const int ta4 = (threadIdx.x & 15) * 4;   // load side: a-offset in chunk
  const int ra = threadIdx.x >> 2;          // store side: a 0..63
  const int riw = threadIdx.x & 3;          // store side: i-word 0..3
  const int il = iloc + riw * 4;
  const int q = (il >> 3) & 3, s0b = (il >> 5) & 1, s1b = (il >> 6) & 1;
  const int pos = q * 32 + s1b * 16 + s0b * 8 + (il & 7);
  const float invI = invLds[ti];

  for (int c = 0; c < 16; ++c) {
    unsigned char* tb = tile8[c & 1];
    const float4 v = *(const float4*)(src + (size_t)(i0 + ti) * DIMS + c * 64 + ta4);
    const unsigned int p = pk4_fp8(v.x * invI, v.y * invI, v.z * invI, v.w * invI);
    tb[(ta4 + 0) * 20 + ti] = (unsigned char)(p);
    tb[(ta4 + 1) * 20 + ti] = (unsigned char)(p >> 8);
    tb[(ta4 + 2) * 20 + ti] = (unsigned char)(p >> 16);
    tb[(ta4 + 3) * 20 + ti] = (unsigned char)(p >> 24);
    __syncthreads();  // write(c) done; read(c) below overlaps write(c+1) other buf
    const unsigned int dw = *(const unsigned int*)&tb[ra * 20 + riw * 4];
    *(unsigned int*)(Mt + (size_t)(aBase + c * 64 + ra) * N_ROWS + blk * 128 + pos) = dw;
  }
}

// ---------------------------------------------------------------------------
// K2: partial Gram tiles, fp8 MFMA, double-buffered LDS, XCD-swizzled jobs,
// fused last-block square-reduce per tile.
// ---------------------------------------------------------------------------
__global__ __launch_bounds__(256, 2) void gram_partial_kernel(
    const unsigned char* __restrict__ Mt, unsigned short* __restrict__ Gp,
    int* __restrict__ counters, float* __restrict__ out) {
  __shared__ __align__(16) char smem[2][2 * BM * BK];  // 2 x 32 KiB
  __shared__ int lastFlag;
  __shared__ float wsum[4];

  // XCD swizzle: XCD x (round-robin dispatch) gets contiguous job range
  const int job = (blockIdx.x & 7) * (NJOBS / 8) + (blockIdx.x >> 3);
  const int t = job >> 2;
  const int kc = job & 3;
  int I = 0, rem = t;
  while (rem >= (TG - I)) { rem -= (TG - I); ++I; }
  const int J = I + rem;

  const int tid = threadIdx.x, w = tid >> 6, lane = tid & 63;

  const int isB = w >> 1;
  const int rblk = isB ? J : I;
  const int rl = lane >> 3;
  const int cl = (lane & 7) ^ rl;          // chunk swizzle (verified R1..R7)
  const bool skipStage = (isB && I == J);
  const unsigned char* gsrc0 =
      Mt + (size_t)(rblk * BM + (w & 1) * 64 + rl) * N_ROWS + kc * KCHUNK + cl * 16;
  const int ldsOff = isB * 16384 + (w & 1) * 8192;
  const int bOff = (I == J) ? 0 : 16384;

  const int wr = w >> 1, wc = w & 1;
  const int ml = lane & 15, quad = lane >> 4;
  const int ar0 = wr * 64, bc0 = wc * 64;

  f32x4 acc[4][4] = {};

  if (!skipStage) {
    #pragma unroll
    for (int s = 0; s < 8; ++s)
      async_cp16(gsrc0 + (size_t)s * 8 * N_ROWS, smem[0] + ldsOff + s * 1024);
  }

  #pragma unroll
  for (int it = 0; it < NITER; ++it) {
    __syncthreads();
    if (it + 1 < NITER && !skipStage) {
      const unsigned char* g = gsrc0 + (it + 1) * BK;
      char* dst = smem[(it + 1) & 1] + ldsOff;
      #pragma unroll
      for (int s = 0; s < 8; ++s)
        async_cp16(g + (size_t)s * 8 * N_ROWS, dst + s * 1024);
    }
    const char* buf = smem[it & 1];
    longx2 a[4][2], b[4][2];
    #pragma unroll
    for (int i = 0; i < 4; ++i) {
      const int ra = (ar0 + i * 16 + ml) * BK;
      const int rb = (bc0 + i * 16 + ml) * BK;
      #pragma unroll
      for (int s1 = 0; s1 < 2; ++s1) {
        const int slot = ((quad * 2 + s1) ^ (ml & 7)) * 16;
        a[i][s1] = *(const longx2*)(buf + ra + slot);
        b[i][s1] = *(const longx2*)(buf + bOff + rb + slot);
      }
    }
    #pragma unroll
    for (int s1 = 0; s1 < 2; ++s1)
      #pragma unroll
      for (int h = 0; h < 2; ++h)
        #pragma unroll
        for (int i = 0; i < 4; ++i)
          #pragma unroll
          for (int j = 0; j < 4; ++j)
            acc[i][j] = __builtin_amdgcn_mfma_f32_16x16x32_fp8_fp8(
                a[i][s1][h], b[j][s1][h], acc[i][j], 0, 0, 0);
  }

  // slab write: lane-major coalesced bf16 (layout consistent across kc)
  unsigned short* slab = Gp + (size_t)job * (BM * BM) + w * 4096;
  #pragma unroll
  for (int i = 0; i < 4; ++i)
    #pragma unroll
    for (int j = 0; j < 4; ++j) {
      ushort4 o;
      o.x = f2bf(acc[i][j][0]); o.y = f2bf(acc[i][j][1]);
      o.z = f2bf(acc[i][j][2]); o.w = f2bf(acc[i][j][3]);
      *(ushort4*)(slab + (i * 4 + j) * 256 + lane * 4) = o;
    }

  // fused finish: last kc-block of tile t reduces the 4 slabs
  __threadfence();  // release slab writes device-wide
  if (tid == 0) lastFlag = (atomicAdd(&counters[t], 1) == KSPLIT - 1);
  __syncthreads();
  if (!lastFlag) return;
  __threadfence();  // acquire other blocks' slab writes

  const unsigned short* tb = Gp + (size_t)t * (KSPLIT * BM * BM);
  float local = 0.0f;
  #pragma unroll
  for (int seg = 0; seg < 8; ++seg) {
    const unsigned short* base = tb + seg * 2048 + tid * 8;
    float s[8] = {0, 0, 0, 0, 0, 0, 0, 0};
    #pragma unroll
    for (int k2 = 0; k2 < KSPLIT; ++k2) {
      const ushort4 v0 = *(const ushort4*)(base + k2 * (BM * BM));
      const ushort4 v1 = *(const ushort4*)(base + k2 * (BM * BM) + 4);
      s[0] += bf2f(v0.x); s[1] += bf2f(v0.y); s[2] += bf2f(v0.z); s[3] += bf2f(v0.w);
      s[4] += bf2f(v1.x); s[5] += bf2f(v1.y); s[6] += bf2f(v1.z); s[7] += bf2f(v1.w);
    }
    #pragma unroll
    for (int x = 0; x < 8; ++x) local += s[x] * s[x];
  }
  const float sgn = ((I < 8) == (J < 8)) ? 1.0f : -1.0f;
  local *= (I == J ? 1.0f : 2.0f) * sgn;
  #pragma unroll
  for (int off = 32; off > 0; off >>= 1) local += __shfl_xor(local, off);
  if (lane == 0) wsum[w] = local;
  __syncthreads();
  if (tid == 0) {
    const float ts = wsum[0] + wsum[1] + wsum[2] + wsum[3];
    atomicAdd(out, ts * (1.0f / 16773120.0f));  // / (N*(N-1))
  }
}

extern "C" void kernel_launch(void* const* d_in, const int* in_sizes, int n_in,
                              void* d_out, int out_size, void* d_ws, size_t ws_size,
                              hipStream_t stream) {
  const float* fq = (const float*)d_in[0];
  const float* fk = (const float*)d_in[1];
  unsigned char* Mt = (unsigned char*)d_ws;                      // 8 MiB fp8
  unsigned short* Gp = (unsigned short*)(Mt + (size_t)2048 * N_ROWS);  // 17.8 MiB
  int* counters = (int*)(Gp + (size_t)NJOBS * BM * BM);          // 544 B
  float* out = (float*)d_out;

  prep_kernel<<<dim3(256, 2), 256, 0, stream>>>(fq, fk, Mt, out, counters);
  gram_partial_kernel<<<NJOBS, 256, 0, stream>>>(Mt, Gp, counters, out);
}

// Round 9
// 120.753 us; speedup vs baseline: 1.5171x; 1.5171x over previous
//
#include <hip/hip_runtime.h>
#include <stdint.h>

// N=4096, D=1024 -> M = [Q|K] : 4096 x 2048, Mt = M^T (fp8 e4m3, K-permuted)
// loss = [ sum_{a,b} s_a s_b (M^T M)_ab^2 ] / (N*(N-1)), s_a=+1 (a<1024), -1 else
// R9 = R6's proven gram + square_reduce (no fence, no XCD swizzle, no fused
// finish — R8 showed device-scope fences cost ~60us) + R8's fused prep
// (coalesced norm+transpose+fp8; old transpose had 4KB-stride scalar reads).
#define N_ROWS 4096
#define DIMS   1024
#define BM 128
#define BK 128         // fp8 elements per LDS row = 128 bytes
#define TG 16
#define NTRI 136
#define KSPLIT 4
#define KCHUNK 1024    // 4096/KSPLIT (fp8 bytes)
#define NJOBS  (NTRI * KSPLIT) // 544

typedef __attribute__((ext_vector_type(2))) long longx2;
typedef __attribute__((ext_vector_type(4))) float f32x4;

__device__ __forceinline__ unsigned short f2bf(float f) {
  union { float f; unsigned int u; } c; c.f = f;
  unsigned int u = c.u;
  return (unsigned short)((u + 0x7fffu + ((u >> 16) & 1u)) >> 16);
}
__device__ __forceinline__ float bf2f(unsigned short v) {
  union { float f; unsigned int u; } c; c.u = ((unsigned int)v) << 16;
  return c.f;
}
// pack 4 floats -> 4 fp8 e4m3 bytes (hardware cvt, OCP on gfx950)
__device__ __forceinline__ unsigned int pk4_fp8(float a, float b, float c, float d) {
  int v = __builtin_amdgcn_cvt_pk_fp8_f32(a, b, 0, false);
  v = __builtin_amdgcn_cvt_pk_fp8_f32(c, d, v, true);
  return (unsigned int)v;
}
// async global->LDS, 16B/lane
__device__ __forceinline__ void async_cp16(const unsigned char* g, void* lds) {
  __builtin_amdgcn_global_load_lds(
      (const __attribute__((address_space(1))) void*)g,
      (__attribute__((address_space(3))) void*)lds, 16, 0, 0);
}

// ---------------------------------------------------------------------------
// K1: fused prep. Block = 16 rows of one source (grid 256 x {q,k}).
// Phase 1: row norms from coalesced float4 reads. Phase 2: re-read same rows
// (L2-hot, same CU), scale, fp8-pack, transpose via double-buffered LDS byte
// tile, write Mt K-permuted (pos = q*32+s1*16+s0*8+j for i = s1*64+s0*32+q*8+j).
// Also zeroes d_out.
// ---------------------------------------------------------------------------
__global__ __launch_bounds__(256) void prep_kernel(
    const float* __restrict__ fq, const float* __restrict__ fk,
    unsigned char* __restrict__ Mt, float* __restrict__ out) {
  if (blockIdx.x == 0 && blockIdx.y == 0 && threadIdx.x == 0) out[0] = 0.0f;
  const int i0 = blockIdx.x * 16;
  const float* src = blockIdx.y ? fk : fq;
  const int aBase = blockIdx.y ? DIMS : 0;

  __shared__ float invLds[16];
  __shared__ unsigned char tile8[2][64 * 20];  // [buf][a_local*20 + i], pitch 20

  const int w = threadIdx.x >> 6, lane = threadIdx.x & 63;
  #pragma unroll
  for (int rr = 0; rr < 4; ++rr) {
    const int r = w * 4 + rr;
    const float4* s4 = (const float4*)(src + (size_t)(i0 + r) * DIMS);
    float ss = 0.0f;
    #pragma unroll
    for (int s = 0; s < 4; ++s) {
      float4 v = s4[lane + 64 * s];
      ss += v.x * v.x + v.y * v.y + v.z * v.z + v.w * v.w;
    }
    #pragma unroll
    for (int off = 32; off > 0; off >>= 1) ss += __shfl_xor(ss, off);
    if (lane == 0) invLds[r] = 1.0f / sqrtf(ss);  // eps cancel ~3e-9 rel
  }
  __syncthreads();

  const int iloc = i0 & 127;
  const int blk = i0 >> 7;
  const int ti = threadIdx.x >> 4;          // load side: i 0..15
  const int ta4 = (threadIdx.x & 15) * 4;   // load side: a-offset in chunk
  const int ra = threadIdx.x >> 2;          // store side: a 0..63
  const int riw = threadIdx.x & 3;          // store side: i-word 0..3
  const int il = iloc + riw * 4;
  const int q = (il >> 3) & 3, s0b = (il >> 5) & 1, s1b = (il >> 6) & 1;
  const int pos = q * 32 + s1b * 16 + s0b * 8 + (il & 7);
  const float invI = invLds[ti];

  for (int c = 0; c < 16; ++c) {
    unsigned char* tb = tile8[c & 1];
    const float4 v = *(const float4*)(src + (size_t)(i0 + ti) * DIMS + c * 64 + ta4);
    const unsigned int p = pk4_fp8(v.x * invI, v.y * invI, v.z * invI, v.w * invI);
    tb[(ta4 + 0) * 20 + ti] = (unsigned char)(p);
    tb[(ta4 + 1) * 20 + ti] = (unsigned char)(p >> 8);
    tb[(ta4 + 2) * 20 + ti] = (unsigned char)(p >> 16);
    tb[(ta4 + 3) * 20 + ti] = (unsigned char)(p >> 24);
    __syncthreads();  // write(c) done; read(c) overlaps write(c+1) in other buf
    const unsigned int dw = *(const unsigned int*)&tb[ra * 20 + riw * 4];
    *(unsigned int*)(Mt + (size_t)(aBase + c * 64 + ra) * N_ROWS + blk * 128 + pos) = dw;
  }
}

// ---------------------------------------------------------------------------
// K2: partial Gram tiles, fp8 MFMA (exact R6 core: single-buffered 32 KiB LDS,
// natural job order, no fences). Stores raw bf16 partial to its slab.
// ---------------------------------------------------------------------------
__global__ __launch_bounds__(256, 2) void gram_partial_kernel(
    const unsigned char* __restrict__ Mt, unsigned short* __restrict__ Gp) {
  __shared__ __align__(16) char smem[2 * BM * BK];  // 32 KiB: A + B panels

  const int t = blockIdx.x >> 2;
  const int kc = blockIdx.x & 3;
  int I = 0, rem = t;
  while (rem >= (TG - I)) { rem -= (TG - I); ++I; }
  const int J = I + rem;

  const int tid = threadIdx.x, w = tid >> 6, lane = tid & 63;

  const int isB = w >> 1;
  const int rblk = isB ? J : I;
  const int rl = lane >> 3;
  const int cl = (lane & 7) ^ rl;          // chunk swizzle (verified R1..R8)
  const bool skipStage = (isB && I == J);
  const unsigned char* gsrc0 =
      Mt + (size_t)(rblk * BM + (w & 1) * 64 + rl) * N_ROWS + kc * KCHUNK + cl * 16;
  char* ldsBase = smem + isB * 16384 + (w & 1) * 8192;
  const int bOff = (I == J) ? 0 : 16384;

  const int wr = w >> 1, wc = w & 1;
  const int ml = lane & 15, quad = lane >> 4;
  const int ar0 = wr * 64, bc0 = wc * 64;

  f32x4 acc[4][4] = {};

  for (int kk = 0; kk < KCHUNK; kk += BK) {
    if (!skipStage) {
      const unsigned char* g = gsrc0 + kk;
      #pragma unroll
      for (int s = 0; s < 8; ++s)
        async_cp16(g + (size_t)s * 8 * N_ROWS, ldsBase + s * 1024);
    }
    __syncthreads();
    longx2 a[4][2], b[4][2];
    #pragma unroll
    for (int i = 0; i < 4; ++i) {
      const int ra = (ar0 + i * 16 + ml) * BK;
      const int rb = (bc0 + i * 16 + ml) * BK;
      #pragma unroll
      for (int s1 = 0; s1 < 2; ++s1) {
        const int slot = ((quad * 2 + s1) ^ (ml & 7)) * 16;
        a[i][s1] = *(const longx2*)(smem + ra + slot);
        b[i][s1] = *(const longx2*)(smem + bOff + rb + slot);
      }
    }
    #pragma unroll
    for (int s1 = 0; s1 < 2; ++s1)
      #pragma unroll
      for (int h = 0; h < 2; ++h)
        #pragma unroll
        for (int i = 0; i < 4; ++i)
          #pragma unroll
          for (int j = 0; j < 4; ++j)
            acc[i][j] = __builtin_amdgcn_mfma_f32_16x16x32_fp8_fp8(
                a[i][s1][h], b[j][s1][h], acc[i][j], 0, 0, 0);
    __syncthreads();
  }

  // epilogue: lane-major coalesced bf16 slab (layout consistent across kc)
  unsigned short* slab = Gp + (size_t)blockIdx.x * (BM * BM) + w * 4096;
  #pragma unroll
  for (int i = 0; i < 4; ++i)
    #pragma unroll
    for (int j = 0; j < 4; ++j) {
      ushort4 o;
      o.x = f2bf(acc[i][j][0]); o.y = f2bf(acc[i][j][1]);
      o.z = f2bf(acc[i][j][2]); o.w = f2bf(acc[i][j][3]);
      *(ushort4*)(slab + (i * 4 + j) * 256 + lane * 4) = o;
    }
}

// ---------------------------------------------------------------------------
// K3: sum KSPLIT partials (fp32), square, sign/weight, reduce -> atomicAdd.
// ---------------------------------------------------------------------------
__global__ __launch_bounds__(256) void square_reduce_kernel(
    const unsigned short* __restrict__ Gp, float* __restrict__ out) {
  __shared__ float wsum[4];
  const int t = blockIdx.x >> 3;
  const int seg = blockIdx.x & 7;
  int I = 0, rem = t;
  while (rem >= (TG - I)) { rem -= (TG - I); ++I; }
  const int J = I + rem;

  const unsigned short* base =
      Gp + (size_t)t * (KSPLIT * BM * BM) + seg * 2048 + threadIdx.x * 8;
  float s[8] = {0, 0, 0, 0, 0, 0, 0, 0};
  #pragma unroll
  for (int kc = 0; kc < KSPLIT; ++kc) {
    const ushort4 v0 = *(const ushort4*)(base + kc * (BM * BM));
    const ushort4 v1 = *(const ushort4*)(base + kc * (BM * BM) + 4);
    s[0] += bf2f(v0.x); s[1] += bf2f(v0.y); s[2] += bf2f(v0.z); s[3] += bf2f(v0.w);
    s[4] += bf2f(v1.x); s[5] += bf2f(v1.y); s[6] += bf2f(v1.z); s[7] += bf2f(v1.w);
  }
  float local = 0.0f;
  #pragma unroll
  for (int x = 0; x < 8; ++x) local += s[x] * s[x];

  const float sgn = ((I < 8) == (J < 8)) ? 1.0f : -1.0f;
  local *= (I == J ? 1.0f : 2.0f) * sgn;

  #pragma unroll
  for (int off = 32; off > 0; off >>= 1) local += __shfl_xor(local, off);
  const int w = threadIdx.x >> 6, lane = threadIdx.x & 63;
  if (lane == 0) wsum[w] = local;
  __syncthreads();
  if (threadIdx.x == 0) {
    const float ts = wsum[0] + wsum[1] + wsum[2] + wsum[3];
    atomicAdd(out, ts * (1.0f / 16773120.0f));  // / (N*(N-1))
  }
}

extern "C" void kernel_launch(void* const* d_in, const int* in_sizes, int n_in,
                              void* d_out, int out_size, void* d_ws, size_t ws_size,
                              hipStream_t stream) {
  const float* fq = (const float*)d_in[0];
  const float* fk = (const float*)d_in[1];
  unsigned char* Mt = (unsigned char*)d_ws;                      // 8 MiB fp8
  unsigned short* Gp = (unsigned short*)(Mt + (size_t)2048 * N_ROWS);  // 17.8 MiB
  float* out = (float*)d_out;

  prep_kernel<<<dim3(256, 2), 256, 0, stream>>>(fq, fk, Mt, out);
  gram_partial_kernel<<<NJOBS, 256, 0, stream>>>(Mt, Gp);
  square_reduce_kernel<<<NTRI * 8, 256, 0, stream>>>(Gp, out);
}